// Round 1
// 199.649 us; speedup vs baseline: 1.0144x; 1.0144x over previous
//
#include <hip/hip_runtime.h>
#include <math.h>

// GCN 2-layer, N=100000, E=3200000, feats 2->16->2.
// R8: (a) degree folded into pass2 via 2048-bin LDS hist + non-atomic per-chunk
//     partials -> k_degree (full 12.8MB slotsF walk + 3.2M LDS atomics) replaced
//     by a ~3us elementwise k_dinv (sum 9 partials, rsqrt, scale x).
//     (b) agg kernels 512->256 threads/block: 8 co-resident blocks/CU instead of
//     4, so independent block phases overlap (latency-bound regime: occupancy
//     was 51%, VALUBusy 2%, HBM 3% -> pure stall); each thread now covers 8
//     edges (2 int4 iters) for deeper per-thread memory pipelining.
// Two-level radix partition (R7) retained:
//  pass1: edges -> 49 coarse buckets (2048 nodes), register-held 8192-edge
//         chunks, 1 reservation atomic per (chunk,bin).
//  pass2: coarse region -> 32 fine buckets (64 nodes) + degree histogram.

constexpr int N = 100000;
constexpr int LOGB = 6;
constexpr int BNODES = 1 << LOGB;             // 64 nodes / fine bucket
constexpr int K = (N + BNODES - 1) / BNODES;  // 1563 fine buckets w/ nodes
constexpr int KF = 49 * 32;                   // fine buckets allocated (1568)
constexpr int CAPF = 2560;                    // fine cap: mean 2048 + ~11 sigma
constexpr int NC = 49;                        // coarse buckets (dst>>11)
constexpr int CAP1 = 68608;                   // coarse cap: mean 65306 + ~13 sigma
constexpr int BSP = 512;
constexpr int ECHUNK = 8192;
constexpr int EPT = ECHUNK / BSP;             // 16 edges/thread, in registers
constexpr int MAXCH = 9;                      // chunks per coarse region (9*8192 >= CAP1)
constexpr int BAGG = 256;                     // agg/degree block size (R8)

__global__ __launch_bounds__(BSP) void k_pass1(const int* __restrict__ src,
                                               const int* __restrict__ dst, int E,
                                               int* __restrict__ gfill1,
                                               int* __restrict__ slotsC) {
    __shared__ int hist[NC];
    __shared__ int base[NC];
    int t = threadIdx.x;
    if (t < NC) hist[t] = 0;
    __syncthreads();
    int s[EPT], d[EPT];
    int ebase = blockIdx.x * ECHUNK + t * EPT;
#pragma unroll
    for (int k = 0; k < EPT / 4; k++) {
        int idx = ebase + 4 * k;
        if (idx + 3 < E) {
            *(int4*)(s + 4 * k) = *(const int4*)(src + idx);
            *(int4*)(d + 4 * k) = *(const int4*)(dst + idx);
        } else {
            for (int j = 0; j < 4; j++) {
                s[4 * k + j] = (idx + j < E) ? src[idx + j] : -1;
                d[4 * k + j] = (idx + j < E) ? dst[idx + j] : -1;
            }
        }
    }
#pragma unroll
    for (int k = 0; k < EPT; k++)
        if (d[k] >= 0) atomicAdd(&hist[d[k] >> 11], 1);
    __syncthreads();
    if (t < NC) {
        int c = hist[t];
        base[t] = c ? atomicAdd(&gfill1[t], c) : 0;  // device reservation atomic
        hist[t] = 0;                                  // reuse as cursor
    }
    __syncthreads();
#pragma unroll
    for (int k = 0; k < EPT; k++) {
        if (d[k] >= 0) {
            int bin = d[k] >> 11;
            int r = atomicAdd(&hist[bin], 1);  // LDS
            int pos = base[bin] + r;
            if (pos < CAP1) slotsC[bin * CAP1 + pos] = (s[k] << 11) | (d[k] & 2047);
        }
    }
}

// pass2: fine radix + per-region degree histogram (R8).
__global__ __launch_bounds__(BSP) void k_pass2(const int* __restrict__ gfill1,
                                               const int* __restrict__ slotsC,
                                               int* __restrict__ gfillF,
                                               int* __restrict__ slotsF,
                                               int* __restrict__ degPart) {
    __shared__ int hist[32];
    __shared__ int base[32];
    __shared__ int dh[2048];
    int c = blockIdx.x / MAXCH;
    int j = blockIdx.x % MAXCH;
    int fill = min(gfill1[c], CAP1);
    int e0 = j * ECHUNK;
    int t = threadIdx.x;
    int* dpRow = degPart + blockIdx.x * 2048;
    if (e0 >= fill) {  // uniform per block, before any sync
        for (int i = t; i < 2048; i += BSP) dpRow[i] = 0;
        return;
    }
    int e1 = min(fill, e0 + ECHUNK);
    if (t < 32) hist[t] = 0;
    for (int i = t; i < 2048; i += BSP) dh[i] = 0;
    __syncthreads();
    const int* row = slotsC + c * CAP1;
    int v[EPT];
    int ebase = e0 + t * EPT;
#pragma unroll
    for (int k = 0; k < EPT / 4; k++) {
        int idx = ebase + 4 * k;
        if (idx + 3 < e1) {
            *(int4*)(v + 4 * k) = *(const int4*)(row + idx);
        } else {
            for (int jj = 0; jj < 4; jj++) v[4 * k + jj] = (idx + jj < e1) ? row[idx + jj] : -1;
        }
    }
#pragma unroll
    for (int k = 0; k < EPT; k++)
        if (v[k] >= 0) {
            atomicAdd(&hist[(v[k] >> 6) & 31], 1);
            atomicAdd(&dh[v[k] & 2047], 1);  // degree hist, 2048 bins: low contention
        }
    __syncthreads();
    if (t < 32) {
        int cc = hist[t];
        base[t] = cc ? atomicAdd(&gfillF[c * 32 + t], cc) : 0;
        hist[t] = 0;
    }
    __syncthreads();
#pragma unroll
    for (int k = 0; k < EPT; k++) {
        if (v[k] >= 0) {
            int b = (v[k] >> 6) & 31;
            int r = atomicAdd(&hist[b], 1);  // LDS
            int pos = base[b] + r;
            if (pos < CAPF)
                slotsF[(c * 32 + b) * CAPF + pos] = ((v[k] >> 11) << 6) | (v[k] & 63);
        }
    }
    // dh finalized before first sync; coalesced non-atomic partial write.
    for (int i = t; i < 2048; i += BSP) dpRow[i] = dh[i];
}

// elementwise: deg = sum of 9 chunk partials; dinv = rsqrt(deg+1); sx = x*dinv
__global__ __launch_bounds__(BAGG) void k_dinv(const int* __restrict__ degPart,
                                               const float* __restrict__ x,
                                               float* __restrict__ dinv,
                                               float2* __restrict__ sx) {
    int node = blockIdx.x * BAGG + threadIdx.x;
    if (node >= N) return;
    int c = node >> 11, i = node & 2047;
    const int* p = degPart + (size_t)c * MAXCH * 2048 + i;
    int deg = 0;
#pragma unroll
    for (int j = 0; j < MAXCH; j++) deg += p[j * 2048];
    float di = rsqrtf((float)(deg + 1));
    dinv[node] = di;
    float2 xv = ((const float2*)x)[node];
    sx[node] = make_float2(xv.x * di, xv.y * di);
}

// layer1 aggregate (SoA LDS acc) + fused MLP; sz = (h@W2)*di
__global__ __launch_bounds__(BAGG) void k_agg1(const int* __restrict__ gfillF,
                                               const int* __restrict__ slotsF,
                                               const float* __restrict__ dinv,
                                               const float2* __restrict__ sx,
                                               const float* __restrict__ W1,
                                               const float* __restrict__ b1,
                                               const float* __restrict__ W2,
                                               float2* __restrict__ sz) {
    __shared__ float accX[BNODES], accY[BNODES];
    __shared__ float sW1[32], sb1[16], sW2[32];
    int t = threadIdx.x;
    if (t < 32) sW1[t] = W1[t];
    if (t >= 32 && t < 48) sb1[t - 32] = b1[t - 32];
    if (t >= 48 && t < 80) sW2[t - 48] = W2[t - 48];
    if (t < BNODES) { accX[t] = 0.f; accY[t] = 0.f; }
    __syncthreads();
    int b = blockIdx.x;
    int count = min(gfillF[b], CAPF);
    const int* row = slotsF + b * CAPF;
    int nvec = count & ~3;
    for (int j = 4 * t; j < nvec; j += 4 * BAGG) {
        int4 p = *(const int4*)(row + j);
        float2 v0 = sx[p.x >> LOGB], v1 = sx[p.y >> LOGB];
        float2 v2 = sx[p.z >> LOGB], v3 = sx[p.w >> LOGB];
        atomicAdd(&accX[p.x & (BNODES - 1)], v0.x);
        atomicAdd(&accY[p.x & (BNODES - 1)], v0.y);
        atomicAdd(&accX[p.y & (BNODES - 1)], v1.x);
        atomicAdd(&accY[p.y & (BNODES - 1)], v1.y);
        atomicAdd(&accX[p.z & (BNODES - 1)], v2.x);
        atomicAdd(&accY[p.z & (BNODES - 1)], v2.y);
        atomicAdd(&accX[p.w & (BNODES - 1)], v3.x);
        atomicAdd(&accY[p.w & (BNODES - 1)], v3.y);
    }
    for (int j = nvec + t; j < count; j += BAGG) {
        int p = row[j];
        float2 v = sx[p >> LOGB];
        atomicAdd(&accX[p & (BNODES - 1)], v.x);
        atomicAdd(&accY[p & (BNODES - 1)], v.y);
    }
    __syncthreads();
    if (t < BNODES) {
        int node = b * BNODES + t;
        if (node < N) {
            float di = dinv[node];
            float2 sv = sx[node];
            float a0 = (accX[t] + sv.x) * di;
            float a1 = (accY[t] + sv.y) * di;
            float z0 = 0.f, z1 = 0.f;
#pragma unroll
            for (int k = 0; k < 16; k++) {
                float h = fmaf(a0, sW1[k], fmaf(a1, sW1[16 + k], sb1[k]));
                h = fmaxf(h, 0.f);
                z0 = fmaf(h, sW2[2 * k + 0], z0);
                z1 = fmaf(h, sW2[2 * k + 1], z1);
            }
            sz[node] = make_float2(z0 * di, z1 * di);
        }
    }
}

// layer2 aggregate + bias + log_softmax
__global__ __launch_bounds__(BAGG) void k_agg2(const int* __restrict__ gfillF,
                                               const int* __restrict__ slotsF,
                                               const float* __restrict__ dinv,
                                               const float2* __restrict__ sz,
                                               const float* __restrict__ b2,
                                               float2* __restrict__ out) {
    __shared__ float accX[BNODES], accY[BNODES];
    int b = blockIdx.x, t = threadIdx.x;
    if (t < BNODES) { accX[t] = 0.f; accY[t] = 0.f; }
    __syncthreads();
    int count = min(gfillF[b], CAPF);
    const int* row = slotsF + b * CAPF;
    int nvec = count & ~3;
    for (int j = 4 * t; j < nvec; j += 4 * BAGG) {
        int4 p = *(const int4*)(row + j);
        float2 v0 = sz[p.x >> LOGB], v1 = sz[p.y >> LOGB];
        float2 v2 = sz[p.z >> LOGB], v3 = sz[p.w >> LOGB];
        atomicAdd(&accX[p.x & (BNODES - 1)], v0.x);
        atomicAdd(&accY[p.x & (BNODES - 1)], v0.y);
        atomicAdd(&accX[p.y & (BNODES - 1)], v1.x);
        atomicAdd(&accY[p.y & (BNODES - 1)], v1.y);
        atomicAdd(&accX[p.z & (BNODES - 1)], v2.x);
        atomicAdd(&accY[p.z & (BNODES - 1)], v2.y);
        atomicAdd(&accX[p.w & (BNODES - 1)], v3.x);
        atomicAdd(&accY[p.w & (BNODES - 1)], v3.y);
    }
    for (int j = nvec + t; j < count; j += BAGG) {
        int p = row[j];
        float2 v = sz[p >> LOGB];
        atomicAdd(&accX[p & (BNODES - 1)], v.x);
        atomicAdd(&accY[p & (BNODES - 1)], v.y);
    }
    __syncthreads();
    if (t < BNODES) {
        int node = b * BNODES + t;
        if (node < N) {
            float di = dinv[node];
            float2 sv = sz[node];
            float v0 = fmaf(accX[t] + sv.x, di, b2[0]);
            float v1 = fmaf(accY[t] + sv.y, di, b2[1]);
            float m = fmaxf(v0, v1);
            float lse = m + logf(expf(v0 - m) + expf(v1 - m));
            out[node] = make_float2(v0 - lse, v1 - lse);
        }
    }
}

extern "C" void kernel_launch(void* const* d_in, const int* in_sizes, int n_in,
                              void* d_out, int out_size, void* d_ws, size_t ws_size,
                              hipStream_t stream) {
    const float* x  = (const float*)d_in[0];
    const int*   ei = (const int*)d_in[1];
    const float* W1 = (const float*)d_in[2];
    const float* b1 = (const float*)d_in[3];
    const float* W2 = (const float*)d_in[4];
    const float* b2 = (const float*)d_in[5];

    const int E = in_sizes[1] / 2;
    const int* src = ei;
    const int* dst = ei + E;
    const int GP = (E + ECHUNK - 1) / ECHUNK;  // 391

    char* ws = (char*)d_ws;
    size_t off = 0;
    auto alloc = [&](size_t bytes) {
        char* p = ws + off;
        off += (bytes + 511) & ~size_t(511);
        return p;
    };
    int*    fills   = (int*)alloc((NC + KF) * sizeof(int));  // gfill1 + gfillF
    float*  dinv    = (float*)alloc(N * sizeof(float));
    float2* sx      = (float2*)alloc(N * sizeof(float2));
    float2* sz      = (float2*)alloc(N * sizeof(float2));
    int*    slotsC  = (int*)alloc((size_t)NC * CAP1 * sizeof(int));          // 13.4 MB
    int*    slotsF  = (int*)alloc((size_t)KF * CAPF * sizeof(int));          // 16.1 MB
    int*    degPart = (int*)alloc((size_t)NC * MAXCH * 2048 * sizeof(int));  // 3.6 MB
    int* gfill1 = fills;
    int* gfillF = fills + NC;

    hipMemsetAsync(fills, 0, (NC + KF) * sizeof(int), stream);

    k_pass1<<<GP, BSP, 0, stream>>>(src, dst, E, gfill1, slotsC);
    k_pass2<<<NC * MAXCH, BSP, 0, stream>>>(gfill1, slotsC, gfillF, slotsF, degPart);
    k_dinv<<<(N + BAGG - 1) / BAGG, BAGG, 0, stream>>>(degPart, x, dinv, sx);
    k_agg1<<<K, BAGG, 0, stream>>>(gfillF, slotsF, dinv, sx, W1, b1, W2, sz);
    k_agg2<<<K, BAGG, 0, stream>>>(gfillF, slotsF, dinv, sz, b2, (float2*)d_out);
}